// Round 12
// baseline (1461.048 us; speedup 1.0000x reference)
//
#include <hip/hip_runtime.h>

// FusedMoE: T=4096 tokens, H=2048 hidden, I=4096 intermediate, E=8 experts, K=2 top-k.
// Pipeline: routing -> fp32->bf16 pre-convert -> grouped gate_up GEMM (+silu*mul)
//           -> grouped down GEMM (*weight, atomic-combine into out) . The separate
//           combine kernel is FUSED into gemm2 (r12): out is zero-initialized and
//           gemm2 atomicAdds w*acc per element. Bit-exact vs the old dout+combine
//           path: each element gets exactly 2 contributions, fp32 add is
//           commutative bit-for-bit and 0+x==x.
// == GEMM structure = r8 (session best: 1451us total; gemm1 328us @ MfmaUtil
// 38.8, FETCH 325MB; gemm2 ~220us) ==
// Both GEMMs: 256-thread blocks, BK=64, single-buffered B + DOUBLE-BUFFERED A
// with counted vmcnt: stage B(t) -> stage A(t+1) -> s_waitcnt vmcnt(4) (A(t+1)
// stays in flight across the barrier) -> s_barrier -> compute -> s_barrier.
// vmcnt(0) only at the tail iteration.
// LDS swizzle (BK=64, 128B rows = 8x16B chunks): store chunk c at c ^ (row&7);
//   read chunk (ks*4+q) ^ (lm&7). Measured SQ_LDS_BANK_CONFLICT = 0.
// Block order: DEFAULT (z=expert outermost). Do NOT XCD-swizzle (r10): default
// dispatch already serializes experts so the active B-panel (33MB) L3-fits;
// forcing all 8 experts concurrent = 268MB > 256MB L3 -> FETCH doubled, +57us.
// History: BK=32 schedules (r2/r4/r6) ~410us vs 358 (per-iter fixed cost);
// full-dbuf 512-thr (r9) 522us; gemm2 BK=128 (r7) -33us; gemm1 launch_bounds
// MUST stay (256,2) — dual acc spills at (256,3) (r3: WRITE 65MB->3.7GB).
// 8-phase 256^2 rewrite rejected: grouped-GEMM incremental over counted-vmcnt
// 2ph is ~+10% (catalog m248v2) at high one-shot race risk; gemm1's 3-operand
// tile does not fit the template's LDS budget.

#define T_TOK 4096
#define H_DIM 2048
#define I_DIM 4096
#define E_NUM 8
#define K_TOP 2
#define NSLOT (T_TOK * K_TOP)   // 8192 total (token,k) slots

#define BM 128
#define BN 128
#define BK 64
#define LDKO 72                 // old fallback path only: 64 + 8 bf16 pad

typedef float f32x4 __attribute__((ext_vector_type(4)));
typedef __bf16 bf16x8 __attribute__((ext_vector_type(8)));
typedef unsigned int u32x4 __attribute__((ext_vector_type(4)));

static __device__ __forceinline__ unsigned short f2bf(float f) {
  // round-to-nearest-even fp32 -> bf16 (inputs are finite)
  unsigned u = __float_as_uint(f);
  u += 0x7FFFu + ((u >> 16) & 1u);
  return (unsigned short)(u >> 16);
}

static __device__ __forceinline__ unsigned long long pack4bf(float x0, float x1, float x2, float x3) {
  unsigned lo = (unsigned)f2bf(x0) | ((unsigned)f2bf(x1) << 16);
  unsigned hi = (unsigned)f2bf(x2) | ((unsigned)f2bf(x3) << 16);
  return (unsigned long long)lo | ((unsigned long long)hi << 32);
}

// async 16B/lane global->LDS. LDS dest is wave-uniform base + lane*16 (linear);
// per-lane global source carries the swizzle.
static __device__ __forceinline__ void gload16(void* lds, const void* g) {
  __builtin_amdgcn_global_load_lds(
      (const __attribute__((address_space(1))) unsigned int*)(g),
      (__attribute__((address_space(3))) unsigned int*)(lds), 16, 0, 0);
}

// ---------------------------------------------------------------- routing ---
__global__ void routing_kernel(const float* __restrict__ tw,
                               const int* __restrict__ ids,
                               int* __restrict__ offsets,      // [E+1]
                               int* __restrict__ stok,         // [NSLOT] token id per slot
                               float* __restrict__ sw,         // [NSLOT] renorm weight per slot
                               int* __restrict__ slot_of) {    // [NSLOT] slot per (t,k)
  __shared__ int cnt[E_NUM];
  __shared__ int cur[E_NUM];
  __shared__ int basesh[E_NUM + 1];
  int tid = threadIdx.x;
  if (tid < E_NUM) cnt[tid] = 0;
  __syncthreads();
  for (int idx = tid; idx < NSLOT; idx += 256) atomicAdd(&cnt[ids[idx]], 1);
  __syncthreads();
  if (tid == 0) {
    int acc = 0;
    for (int e = 0; e < E_NUM; ++e) { basesh[e] = acc; acc += cnt[e]; }
    basesh[E_NUM] = acc;
    for (int e = 0; e <= E_NUM; ++e) offsets[e] = basesh[e];
  }
  __syncthreads();
  if (tid < E_NUM) cur[tid] = basesh[tid];
  __syncthreads();
  for (int idx = tid; idx < NSLOT; idx += 256) {
    int t = idx >> 1;
    float w0 = tw[t * 2], w1 = tw[t * 2 + 1];
    float w = ((idx & 1) ? w1 : w0) / (w0 + w1);
    int e = ids[idx];
    int slot = atomicAdd(&cur[e], 1);
    stok[slot] = t;
    sw[slot] = w;
    slot_of[idx] = slot;
  }
}

// ------------------------------------------------------ fp32 -> bf16 convert ---
__global__ __launch_bounds__(256) void cvt_bf16_kernel(const float* __restrict__ in,
                                                       unsigned short* __restrict__ out,
                                                       long long n8) {
  long long stride = (long long)gridDim.x * 256;
  for (long long i = (long long)blockIdx.x * 256 + threadIdx.x; i < n8; i += stride) {
    long long o = i * 8;
    f32x4 v0 = *(const f32x4*)(in + o);
    f32x4 v1 = *(const f32x4*)(in + o + 4);
    unsigned long long p0 = pack4bf(v0[0], v0[1], v0[2], v0[3]);
    unsigned long long p1 = pack4bf(v1[0], v1[1], v1[2], v1[3]);
    u32x4 st;
    st[0] = (unsigned)p0; st[1] = (unsigned)(p0 >> 32);
    st[2] = (unsigned)p1; st[3] = (unsigned)(p1 >> 32);
    *(u32x4*)(out + o) = st;
  }
}

// ------------------------------------------------------------- zero output ---
__global__ __launch_bounds__(256) void zero_out_kernel(f32x4* __restrict__ out4) {
  long long stride = (long long)gridDim.x * 256;
  f32x4 z = {0.f, 0.f, 0.f, 0.f};
  for (long long i = (long long)blockIdx.x * 256 + threadIdx.x;
       i < (long long)T_TOK * H_DIM / 4; i += stride)
    out4[i] = z;
}

// ------------------------------------------- gate_up GEMM (bf16) + silu*mul ---
// 128x128 act tile, dual acc (gate+up). BK=64, A double-buffered (counted vmcnt).
__global__ __launch_bounds__(256, 2) void gemm1_bf16_kernel(
    const unsigned short* __restrict__ hb,   // hidden bf16 [T][H]
    const unsigned short* __restrict__ gub,  // gate_up bf16 [E][2I][H]
    const int* __restrict__ offsets, const int* __restrict__ stok,
    unsigned short* __restrict__ act) {
  int e = blockIdx.z;
  int base = offsets[e];
  int cnt = offsets[e + 1] - base;
  int m0 = blockIdx.y * BM;
  if (m0 >= cnt) return;
  int n0 = blockIdx.x * BN;
  int rem = cnt - m0;

  __shared__ __attribute__((aligned(16))) unsigned short As[2][BM * 64];
  __shared__ __attribute__((aligned(16))) unsigned short Bg[BN * 64];
  __shared__ __attribute__((aligned(16))) unsigned short Bu[BN * 64];
  __shared__ int toks[BM];

  int tid = threadIdx.x;
  // safe token for padded rows (block only runs when cnt >= 1)
  if (tid < BM) toks[tid] = (tid < rem) ? stok[base + m0 + tid] : stok[base];
  __syncthreads();

  int lane = tid & 63;
  int wid = tid >> 6;
  int srow = lane >> 3;                  // row within 8-row staging group == row&7
  int scol = ((lane & 7) ^ srow) << 3;   // swizzled source chunk, in shorts

  const unsigned short* wrow = gub + (size_t)e * (2 * (size_t)I_DIM) * H_DIM;
  const unsigned short* pa[4];
  const unsigned short* pg[4];
  const unsigned short* pu[4];
#pragma unroll
  for (int s = 0; s < 4; ++s) {
    int row = wid * 32 + s * 8 + srow;
    pa[s] = hb + (size_t)toks[row] * H_DIM + scol;
    pg[s] = wrow + (size_t)(n0 + row) * H_DIM + scol;
    pu[s] = wrow + (size_t)(I_DIM + n0 + row) * H_DIM + scol;
  }

  int lm = lane & 15;
  int q = lane >> 4;
  int wm = (wid >> 1) * 64;
  int wn = (wid & 1) * 64;
  // swizzled read cols (shorts): chunk (ks*4+q) ^ (lm&7)
  int rc0 = ((q ^ (lm & 7)) << 3);
  int rc1 = (((4 + q) ^ (lm & 7)) << 3);

  f32x4 accg[4][4] = {};
  f32x4 accu[4][4] = {};

  // prologue: stage A tile 0 (4 loads/thread) into As[0]
#pragma unroll
  for (int s = 0; s < 4; ++s)
    gload16(&As[0][(wid * 32 + s * 8) * 64], pa[s]);

  int cur = 0;
  for (int kb = 0; kb < H_DIM; kb += BK) {
    // stage B(t): 8 loads/thread (needed this iter -> drained below)
#pragma unroll
    for (int s = 0; s < 4; ++s) {
      gload16(&Bg[(wid * 32 + s * 8) * 64], pg[s] + kb);
      gload16(&Bu[(wid * 32 + s * 8) * 64], pu[s] + kb);
    }
    if (kb + BK < H_DIM) {
      // stage A(t+1): 4 loads/thread -> allowed to stay in flight (vmcnt 4)
#pragma unroll
      for (int s = 0; s < 4; ++s)
        gload16(&As[cur ^ 1][(wid * 32 + s * 8) * 64], pa[s] + kb + BK);
      __builtin_amdgcn_sched_barrier(0);
      asm volatile("s_waitcnt vmcnt(4)" ::: "memory");
    } else {
      __builtin_amdgcn_sched_barrier(0);
      asm volatile("s_waitcnt vmcnt(0)" ::: "memory");
    }
    __builtin_amdgcn_s_barrier();
    __builtin_amdgcn_sched_barrier(0);
#pragma unroll
    for (int ks = 0; ks < 2; ++ks) {
      int ko = ks ? rc1 : rc0;
      bf16x8 a[4], bg[4], bu[4];
#pragma unroll
      for (int i = 0; i < 4; ++i)
        a[i] = *(const bf16x8*)&As[cur][(wm + i * 16 + lm) * 64 + ko];
#pragma unroll
      for (int j = 0; j < 4; ++j) {
        bg[j] = *(const bf16x8*)&Bg[(wn + j * 16 + lm) * 64 + ko];
        bu[j] = *(const bf16x8*)&Bu[(wn + j * 16 + lm) * 64 + ko];
      }
#pragma unroll
      for (int i = 0; i < 4; ++i)
#pragma unroll
        for (int j = 0; j < 4; ++j) {
          accg[i][j] = __builtin_amdgcn_mfma_f32_16x16x32_bf16(a[i], bg[j], accg[i][j], 0, 0, 0);
          accu[i][j] = __builtin_amdgcn_mfma_f32_16x16x32_bf16(a[i], bu[j], accu[i][j], 0, 0, 0);
        }
    }
    __builtin_amdgcn_sched_barrier(0);
    __builtin_amdgcn_s_barrier();   // protects Bg/Bu + As[cur] overwrite next iter
    cur ^= 1;
  }

  // epilogue: act = silu(gate)*up, bf16 store. D layout: row=q*4+reg, col=lane&15.
#pragma unroll
  for (int i = 0; i < 4; ++i) {
    int mb = wm + i * 16 + q * 4;
#pragma unroll
    for (int r = 0; r < 4; ++r) {
      int m = mb + r;
      if (m < rem) {
        size_t rowoff = (size_t)(base + m0 + m) * I_DIM + n0;
#pragma unroll
        for (int j = 0; j < 4; ++j) {
          int n = wn + j * 16 + lm;
          float g = accg[i][j][r];
          float u = accu[i][j][r];
          float aa = (g / (1.0f + __expf(-g))) * u;
          act[rowoff + n] = f2bf(aa);
        }
      }
    }
  }
}

// ---------------------------------------------- down GEMM (bf16) * weight ---
// BK=64, (256,3), A-prefetch w/ counted vmcnt (r8 proven). Epilogue fused with
// combine: atomicAdd(w*acc) into out[token] (out zero-initialized; 2
// contributions/element; fp32 add commutative bit-for-bit -> bit-exact).
__global__ __launch_bounds__(256, 3) void gemm2_bf16_kernel(
    const unsigned short* __restrict__ act, const unsigned short* __restrict__ dwb,
    const int* __restrict__ offsets, const int* __restrict__ stok,
    const float* __restrict__ sw, float* __restrict__ out) {
  int e = blockIdx.z;
  int base = offsets[e];
  int cnt = offsets[e + 1] - base;
  int m0 = blockIdx.y * BM;
  if (m0 >= cnt) return;
  int n0 = blockIdx.x * BN;
  int rem = cnt - m0;

  __shared__ __attribute__((aligned(16))) unsigned short As[2][BM * 64];
  __shared__ __attribute__((aligned(16))) unsigned short Bs[BN * 64];
  __shared__ float wsl[BM];
  __shared__ int toks[BM];

  int tid = threadIdx.x;
  if (tid < BM) {
    wsl[tid] = (tid < rem) ? sw[base + m0 + tid] : 0.f;
    toks[tid] = (tid < rem) ? stok[base + m0 + tid] : 0;
  }
  __syncthreads();

  int lane = tid & 63;
  int wid = tid >> 6;
  int srow = lane >> 3;
  int scol = ((lane & 7) ^ srow) << 3;

  const unsigned short* dp = dwb + (size_t)e * ((size_t)H_DIM * I_DIM);
  const unsigned short* pa[4];
  const unsigned short* pb[4];
#pragma unroll
  for (int s = 0; s < 4; ++s) {
    int row = wid * 32 + s * 8 + srow;
    pa[s] = act + (size_t)(base + m0 + row) * I_DIM + scol;
    pb[s] = dp + (size_t)(n0 + row) * I_DIM + scol;
  }

  int lm = lane & 15;
  int q = lane >> 4;
  int wm = (wid >> 1) * 64;
  int wn = (wid & 1) * 64;
  int rc0 = ((q ^ (lm & 7)) << 3);
  int rc1 = (((4 + q) ^ (lm & 7)) << 3);

  f32x4 acc[4][4] = {};

  // prologue: stage A (act) tile 0
#pragma unroll
  for (int s = 0; s < 4; ++s)
    gload16(&As[0][(wid * 32 + s * 8) * 64], pa[s]);

  int cur = 0;
  for (int kb = 0; kb < I_DIM; kb += BK) {
    // stage B(t): needed this iter
#pragma unroll
    for (int s = 0; s < 4; ++s)
      gload16(&Bs[(wid * 32 + s * 8) * 64], pb[s] + kb);
    if (kb + BK < I_DIM) {
      // stage A(t+1): stays in flight across the barrier
#pragma unroll
      for (int s = 0; s < 4; ++s)
        gload16(&As[cur ^ 1][(wid * 32 + s * 8) * 64], pa[s] + kb + BK);
      __builtin_amdgcn_sched_barrier(0);
      asm volatile("s_waitcnt vmcnt(4)" ::: "memory");
    } else {
      __builtin_amdgcn_sched_barrier(0);
      asm volatile("s_waitcnt vmcnt(0)" ::: "memory");
    }
    __builtin_amdgcn_s_barrier();
    __builtin_amdgcn_sched_barrier(0);
#pragma unroll
    for (int ks = 0; ks < 2; ++ks) {
      int ko = ks ? rc1 : rc0;
      bf16x8 a[4], b[4];
#pragma unroll
      for (int i = 0; i < 4; ++i)
        a[i] = *(const bf16x8*)&As[cur][(wm + i * 16 + lm) * 64 + ko];
#pragma unroll
      for (int j = 0; j < 4; ++j)
        b[j] = *(const bf16x8*)&Bs[(wn + j * 16 + lm) * 64 + ko];
#pragma unroll
      for (int i = 0; i < 4; ++i)
#pragma unroll
        for (int j = 0; j < 4; ++j)
          acc[i][j] = __builtin_amdgcn_mfma_f32_16x16x32_bf16(a[i], b[j], acc[i][j], 0, 0, 0);
    }
    __builtin_amdgcn_sched_barrier(0);
    __builtin_amdgcn_s_barrier();   // protects Bs + As[cur] overwrite next iter
    cur ^= 1;
  }

  // epilogue: atomic-combine w*acc into out[token][n] (device-scope atomics)
#pragma unroll
  for (int i = 0; i < 4; ++i) {
    int mb = wm + i * 16 + q * 4;
#pragma unroll
    for (int r = 0; r < 4; ++r) {
      int m = mb + r;
      if (m < rem) {
        float w = wsl[m];
        size_t rowoff = (size_t)toks[m] * H_DIM + n0;
#pragma unroll
        for (int j = 0; j < 4; ++j)
          atomicAdd(&out[rowoff + wn + j * 16 + lm], acc[i][j][r] * w);
      }
    }
  }
}

// ==================== OLD PATH (fallback if workspace too small) =============
__global__ __launch_bounds__(256, 2) void gemm1_kernel(
    const float* __restrict__ hidden, const float* __restrict__ gu,
    const int* __restrict__ offsets, const int* __restrict__ stok,
    unsigned short* __restrict__ act) {
  int e = blockIdx.z;
  int base = offsets[e];
  int cnt = offsets[e + 1] - base;
  int m0 = blockIdx.y * BM;
  if (m0 >= cnt) return;
  int n0 = blockIdx.x * BN;
  int rem = cnt - m0;

  __shared__ unsigned short As[BM * LDKO];
  __shared__ unsigned short Bg[BM * LDKO];
  __shared__ unsigned short Bu[BM * LDKO];
  __shared__ int toks[BM];

  int tid = threadIdx.x;
  if (tid < BM) toks[tid] = (tid < rem) ? stok[base + m0 + tid] : -1;
  __syncthreads();

  int lane = tid & 63;
  int wid = tid >> 6;
  int wm = (wid >> 1) * 64;
  int wn = (wid & 1) * 64;
  int lm = lane & 15;
  int q = lane >> 4;

  f32x4 accg[4][4] = {};
  f32x4 accu[4][4] = {};
  const float* gup = gu + (size_t)e * (2 * (size_t)I_DIM * H_DIM);

  for (int kb = 0; kb < H_DIM; kb += 64) {
#pragma unroll
    for (int s = 0; s < 8; ++s) {
      int task = tid + s * 256;
      int row = task >> 4;
      int cg = (task & 15) << 2;
      int tok = toks[row];
      float x0 = 0.f, x1 = 0.f, x2 = 0.f, x3 = 0.f;
      if (tok >= 0) {
        f32x4 v = *(const f32x4*)(hidden + (size_t)tok * H_DIM + kb + cg);
        x0 = v[0]; x1 = v[1]; x2 = v[2]; x3 = v[3];
      }
      *(unsigned long long*)&As[row * LDKO + cg] = pack4bf(x0, x1, x2, x3);
    }
#pragma unroll
    for (int s = 0; s < 8; ++s) {
      int task = tid + s * 256;
      int row = task >> 4;
      int cg = (task & 15) << 2;
      f32x4 vg = *(const f32x4*)(gup + (size_t)(n0 + row) * H_DIM + kb + cg);
      f32x4 vu = *(const f32x4*)(gup + (size_t)(I_DIM + n0 + row) * H_DIM + kb + cg);
      *(unsigned long long*)&Bg[row * LDKO + cg] = pack4bf(vg[0], vg[1], vg[2], vg[3]);
      *(unsigned long long*)&Bu[row * LDKO + cg] = pack4bf(vu[0], vu[1], vu[2], vu[3]);
    }
    __syncthreads();
#pragma unroll
    for (int ks = 0; ks < 2; ++ks) {
      int ko = ks * 32 + q * 8;
      bf16x8 a[4], bg[4], bu[4];
#pragma unroll
      for (int i = 0; i < 4; ++i)
        a[i] = *(const bf16x8*)&As[(wm + i * 16 + lm) * LDKO + ko];
#pragma unroll
      for (int j = 0; j < 4; ++j) {
        bg[j] = *(const bf16x8*)&Bg[(wn + j * 16 + lm) * LDKO + ko];
        bu[j] = *(const bf16x8*)&Bu[(wn + j * 16 + lm) * LDKO + ko];
      }
#pragma unroll
      for (int i = 0; i < 4; ++i)
#pragma unroll
        for (int j = 0; j < 4; ++j) {
          accg[i][j] = __builtin_amdgcn_mfma_f32_16x16x32_bf16(a[i], bg[j], accg[i][j], 0, 0, 0);
          accu[i][j] = __builtin_amdgcn_mfma_f32_16x16x32_bf16(a[i], bu[j], accu[i][j], 0, 0, 0);
        }
    }
    __syncthreads();
  }

#pragma unroll
  for (int i = 0; i < 4; ++i) {
    int mb = wm + i * 16 + q * 4;
#pragma unroll
    for (int r = 0; r < 4; ++r) {
      int m = mb + r;
      if (m < rem) {
        size_t rowoff = (size_t)(base + m0 + m) * I_DIM + n0;
#pragma unroll
        for (int j = 0; j < 4; ++j) {
          int n = wn + j * 16 + lm;
          float g = accg[i][j][r];
          float u = accu[i][j][r];
          float aa = (g / (1.0f + __expf(-g))) * u;
          act[rowoff + n] = f2bf(aa);
        }
      }
    }
  }
}

__global__ __launch_bounds__(256, 2) void gemm2_kernel(
    const unsigned short* __restrict__ act, const float* __restrict__ dwn,
    const int* __restrict__ offsets, const float* __restrict__ sw,
    float* __restrict__ dout) {
  int e = blockIdx.z;
  int base = offsets[e];
  int cnt = offsets[e + 1] - base;
  int m0 = blockIdx.y * BM;
  if (m0 >= cnt) return;
  int n0 = blockIdx.x * BN;
  int rem = cnt - m0;

  __shared__ unsigned short As[BM * LDKO];
  __shared__ unsigned short Bs[BM * LDKO];
  __shared__ float wsl[BM];

  int tid = threadIdx.x;
  if (tid < BM) wsl[tid] = (tid < rem) ? sw[base + m0 + tid] : 0.f;

  int lane = tid & 63;
  int wid = tid >> 6;
  int wm = (wid >> 1) * 64;
  int wn = (wid & 1) * 64;
  int lm = lane & 15;
  int q = lane >> 4;

  f32x4 acc[4][4] = {};
  const float* dp = dwn + (size_t)e * ((size_t)H_DIM * I_DIM);
  const unsigned short* ap = act + (size_t)(base + m0) * I_DIM;

  for (int kb = 0; kb < I_DIM; kb += 64) {
#pragma unroll
    for (int s = 0; s < 4; ++s) {
      int task = tid + s * 256;
      int row = task >> 3;
      int cg = (task & 7) << 3;
      u32x4 v = *(const u32x4*)(ap + (size_t)row * I_DIM + kb + cg);
      *(u32x4*)&As[row * LDKO + cg] = v;
    }
#pragma unroll
    for (int s = 0; s < 8; ++s) {
      int task = tid + s * 256;
      int row = task >> 4;
      int cg = (task & 15) << 2;
      f32x4 v = *(const f32x4*)(dp + (size_t)(n0 + row) * I_DIM + kb + cg);
      *(unsigned long long*)&Bs[row * LDKO + cg] = pack4bf(v[0], v[1], v[2], v[3]);
    }
    __syncthreads();
#pragma unroll
    for (int ks = 0; ks < 2; ++ks) {
      int ko = ks * 32 + q * 8;
      bf16x8 a[4], b[4];
#pragma unroll
      for (int i = 0; i < 4; ++i)
        a[i] = *(const bf16x8*)&As[(wm + i * 16 + lm) * LDKO + ko];
#pragma unroll
      for (int j = 0; j < 4; ++j)
        b[j] = *(const bf16x8*)&Bs[(wn + j * 16 + lm) * LDKO + ko];
#pragma unroll
      for (int i = 0; i < 4; ++i)
#pragma unroll
        for (int j = 0; j < 4; ++j)
          acc[i][j] = __builtin_amdgcn_mfma_f32_16x16x32_bf16(a[i], b[j], acc[i][j], 0, 0, 0);
    }
    __syncthreads();
  }

#pragma unroll
  for (int i = 0; i < 4; ++i) {
    int mb = wm + i * 16 + q * 4;
#pragma unroll
    for (int r = 0; r < 4; ++r) {
      int m = mb + r;
      if (m < rem) {
        float w = wsl[m];
        size_t rowoff = (size_t)(base + m0 + m) * H_DIM + n0;
#pragma unroll
        for (int j = 0; j < 4; ++j)
          dout[rowoff + wn + j * 16 + lm] = acc[i][j][r] * w;
      }
    }
  }
}

// ------------------------------------------------------------------ combine ---
__global__ void combine_kernel(const f32x4* __restrict__ dout4,
                               const int* __restrict__ slot_of,
                               f32x4* __restrict__ out4) {
  int idx = blockIdx.x * 256 + threadIdx.x;   // over T*H/4 = 2M
  int t = idx >> 9;                           // H/4 = 512 float4 per token
  int c = idx & 511;
  int s0 = slot_of[t * 2];
  int s1 = slot_of[t * 2 + 1];
  f32x4 r = dout4[(size_t)s0 * 512 + c] + dout4[(size_t)s1 * 512 + c];
  out4[idx] = r;
}

// ----------------------------------------------------------------- launch ---
extern "C" void kernel_launch(void* const* d_in, const int* in_sizes, int n_in,
                              void* d_out, int out_size, void* d_ws, size_t ws_size,
                              hipStream_t stream) {
  const float* hidden = (const float*)d_in[0];
  const float* tw     = (const float*)d_in[1];
  const int*   ids    = (const int*)d_in[2];
  const float* gu     = (const float*)d_in[3];
  const float* dwn    = (const float*)d_in[4];
  float* out = (float*)d_out;
  char* ws = (char*)d_ws;

  // common routing scratch (first 128 KiB)
  int*   offsets = (int*)ws;
  int*   stok    = (int*)(ws + 256);
  float* swp     = (float*)(ws + 256 + 32768);
  int*   slot_of = (int*)(ws + 256 + 65536);
  const size_t base_off = 1 << 17;
  const size_t act_sz   = (size_t)(NSLOT + BM) * I_DIM * 2;    // bf16, +pad rows

  routing_kernel<<<1, 256, 0, stream>>>(tw, ids, offsets, stok, swp, slot_of);

  // new-path layout:
  //   [base_off]                hidden_bf16   16 MiB
  //   [w_off]                   W region     256 MiB:
  //       gemm1 phase: gu_bf16 (full 256 MiB)
  //       gemm2 phase: down_bf16 [0,128MiB)  (aliases gub, dead after gemm1)
  //   [w_off + 256MiB]          act bf16     ~65 MiB
  const size_t hb_sz  = (size_t)T_TOK * H_DIM * 2;
  const size_t gu_sz  = (size_t)E_NUM * 2 * (size_t)I_DIM * H_DIM * 2;
  const size_t dwn_sz = (size_t)E_NUM * (size_t)H_DIM * I_DIM * 2;
  const size_t w_off  = base_off + hb_sz;
  const size_t need   = w_off + gu_sz + act_sz;

  if (ws_size >= need) {
    unsigned short* hb   = (unsigned short*)(ws + base_off);
    unsigned short* gub  = (unsigned short*)(ws + w_off);
    unsigned short* dwb  = (unsigned short*)(ws + w_off);            // aliases gub (dead after gemm1)
    unsigned short* act  = (unsigned short*)(ws + w_off + gu_sz);

    zero_out_kernel<<<2048, 256, 0, stream>>>((f32x4*)out);
    cvt_bf16_kernel<<<2048, 256, 0, stream>>>(hidden, hb, (long long)T_TOK * H_DIM / 8);
    cvt_bf16_kernel<<<2048, 256, 0, stream>>>(gu, gub, (long long)E_NUM * 2 * I_DIM * H_DIM / 8);
    gemm1_bf16_kernel<<<dim3(I_DIM / BN, NSLOT / BM, E_NUM), 256, 0, stream>>>(hb, gub, offsets, stok, act);
    cvt_bf16_kernel<<<2048, 256, 0, stream>>>(dwn, dwb, (long long)E_NUM * H_DIM * I_DIM / 8);
    gemm2_bf16_kernel<<<dim3(H_DIM / BN, NSLOT / BM, E_NUM), 256, 0, stream>>>(act, dwb, offsets, stok, swp, out);
  } else {
    // fallback: previous fp32-staging path (fits in ~132 MiB)
    unsigned short* act  = (unsigned short*)(ws + base_off);
    float*          dout = (float*)(ws + base_off + act_sz);
    gemm1_kernel<<<dim3(I_DIM / BN, NSLOT / BM, E_NUM), 256, 0, stream>>>(hidden, gu, offsets, stok, act);
    gemm2_kernel<<<dim3(H_DIM / BN, NSLOT / BM, E_NUM), 256, 0, stream>>>(act, dwn, offsets, swp, dout);
    combine_kernel<<<(T_TOK * H_DIM / 4) / 256, 256, 0, stream>>>((const f32x4*)dout, slot_of, (f32x4*)out);
  }
}

// Round 13
// 1451.176 us; speedup vs baseline: 1.0068x; 1.0068x over previous
//
#include <hip/hip_runtime.h>

// FusedMoE: T=4096 tokens, H=2048 hidden, I=4096 intermediate, E=8 experts, K=2 top-k.
// Pipeline: routing -> fp32->bf16 pre-convert -> grouped gate_up GEMM (+silu*mul)
//           -> grouped down GEMM (*weight) -> per-token combine of K=2 slots.
// == FINAL configuration = r11 (session best: 1451.5us; gemm1 328us @ MfmaUtil
// 38.8, FETCH 325MB ~= compulsory; gemm2 ~220us; cvt ~200us compulsory-BW) ==
// Both GEMMs: 256-thread blocks, BK=64, single-buffered B + DOUBLE-BUFFERED A
// with counted vmcnt: stage B(t) -> stage A(t+1) -> s_waitcnt vmcnt(4) (A(t+1)
// stays in flight across the barrier) -> s_barrier -> compute -> s_barrier.
// vmcnt(0) only at the tail iteration.
// LDS swizzle (BK=64, 128B rows = 8x16B chunks): store chunk c at c ^ (row&7);
//   read chunk (ks*4+q) ^ (lm&7). Measured SQ_LDS_BANK_CONFLICT = 0.
// Block order: DEFAULT (z=expert outermost). Do NOT XCD-swizzle (r10): default
// dispatch serializes experts so the active B-panel L3-fits; forcing all 8
// experts concurrent = 268MB > 256MB L3 -> FETCH doubled, +57us.
// Falsified-variant ledger (do not retry without new evidence):
//   BK=32 schedules (r2/r4/r6): ~410us vs 358 (per-iter fixed cost dominates)
//   full-dbuf 512-thread (r9): 522us (MFMA:ds_read ratio, 8-wave lockstep)
//   gemm1 (256,3) (r3): acc spills -> WRITE 65MB->3.7GB, 2.6x regression
//   gemm2 BK=128 (r7): -33us (64KB LDS -> 2 blk/CU, was 3)
//   XCD swizzle (r10): FETCH 325->780MB (L3 thrash)
//   atomic combine-fusion (r12): +9.5us (atomicAdd tax > combine savings)
//   8-phase 256^2: rejected, grouped-GEMM incremental ~+10% (catalog m248v2),
//     gemm1's 3-operand tile doesn't fit the template's LDS budget.

#define T_TOK 4096
#define H_DIM 2048
#define I_DIM 4096
#define E_NUM 8
#define K_TOP 2
#define NSLOT (T_TOK * K_TOP)   // 8192 total (token,k) slots

#define BM 128
#define BN 128
#define BK 64
#define LDKO 72                 // old fallback path only: 64 + 8 bf16 pad

typedef float f32x4 __attribute__((ext_vector_type(4)));
typedef __bf16 bf16x8 __attribute__((ext_vector_type(8)));
typedef unsigned int u32x4 __attribute__((ext_vector_type(4)));

static __device__ __forceinline__ unsigned short f2bf(float f) {
  // round-to-nearest-even fp32 -> bf16 (inputs are finite)
  unsigned u = __float_as_uint(f);
  u += 0x7FFFu + ((u >> 16) & 1u);
  return (unsigned short)(u >> 16);
}

static __device__ __forceinline__ unsigned long long pack4bf(float x0, float x1, float x2, float x3) {
  unsigned lo = (unsigned)f2bf(x0) | ((unsigned)f2bf(x1) << 16);
  unsigned hi = (unsigned)f2bf(x2) | ((unsigned)f2bf(x3) << 16);
  return (unsigned long long)lo | ((unsigned long long)hi << 32);
}

// async 16B/lane global->LDS. LDS dest is wave-uniform base + lane*16 (linear);
// per-lane global source carries the swizzle.
static __device__ __forceinline__ void gload16(void* lds, const void* g) {
  __builtin_amdgcn_global_load_lds(
      (const __attribute__((address_space(1))) unsigned int*)(g),
      (__attribute__((address_space(3))) unsigned int*)(lds), 16, 0, 0);
}

// ---------------------------------------------------------------- routing ---
__global__ void routing_kernel(const float* __restrict__ tw,
                               const int* __restrict__ ids,
                               int* __restrict__ offsets,      // [E+1]
                               int* __restrict__ stok,         // [NSLOT] token id per slot
                               float* __restrict__ sw,         // [NSLOT] renorm weight per slot
                               int* __restrict__ slot_of) {    // [NSLOT] slot per (t,k)
  __shared__ int cnt[E_NUM];
  __shared__ int cur[E_NUM];
  __shared__ int basesh[E_NUM + 1];
  int tid = threadIdx.x;
  if (tid < E_NUM) cnt[tid] = 0;
  __syncthreads();
  for (int idx = tid; idx < NSLOT; idx += 256) atomicAdd(&cnt[ids[idx]], 1);
  __syncthreads();
  if (tid == 0) {
    int acc = 0;
    for (int e = 0; e < E_NUM; ++e) { basesh[e] = acc; acc += cnt[e]; }
    basesh[E_NUM] = acc;
    for (int e = 0; e <= E_NUM; ++e) offsets[e] = basesh[e];
  }
  __syncthreads();
  if (tid < E_NUM) cur[tid] = basesh[tid];
  __syncthreads();
  for (int idx = tid; idx < NSLOT; idx += 256) {
    int t = idx >> 1;
    float w0 = tw[t * 2], w1 = tw[t * 2 + 1];
    float w = ((idx & 1) ? w1 : w0) / (w0 + w1);
    int e = ids[idx];
    int slot = atomicAdd(&cur[e], 1);
    stok[slot] = t;
    sw[slot] = w;
    slot_of[idx] = slot;
  }
}

// ------------------------------------------------------ fp32 -> bf16 convert ---
__global__ __launch_bounds__(256) void cvt_bf16_kernel(const float* __restrict__ in,
                                                       unsigned short* __restrict__ out,
                                                       long long n8) {
  long long stride = (long long)gridDim.x * 256;
  for (long long i = (long long)blockIdx.x * 256 + threadIdx.x; i < n8; i += stride) {
    long long o = i * 8;
    f32x4 v0 = *(const f32x4*)(in + o);
    f32x4 v1 = *(const f32x4*)(in + o + 4);
    unsigned long long p0 = pack4bf(v0[0], v0[1], v0[2], v0[3]);
    unsigned long long p1 = pack4bf(v1[0], v1[1], v1[2], v1[3]);
    u32x4 st;
    st[0] = (unsigned)p0; st[1] = (unsigned)(p0 >> 32);
    st[2] = (unsigned)p1; st[3] = (unsigned)(p1 >> 32);
    *(u32x4*)(out + o) = st;
  }
}

// ------------------------------------------- gate_up GEMM (bf16) + silu*mul ---
// 128x128 act tile, dual acc (gate+up). BK=64, A double-buffered (counted vmcnt).
__global__ __launch_bounds__(256, 2) void gemm1_bf16_kernel(
    const unsigned short* __restrict__ hb,   // hidden bf16 [T][H]
    const unsigned short* __restrict__ gub,  // gate_up bf16 [E][2I][H]
    const int* __restrict__ offsets, const int* __restrict__ stok,
    unsigned short* __restrict__ act) {
  int e = blockIdx.z;
  int base = offsets[e];
  int cnt = offsets[e + 1] - base;
  int m0 = blockIdx.y * BM;
  if (m0 >= cnt) return;
  int n0 = blockIdx.x * BN;
  int rem = cnt - m0;

  __shared__ __attribute__((aligned(16))) unsigned short As[2][BM * 64];
  __shared__ __attribute__((aligned(16))) unsigned short Bg[BN * 64];
  __shared__ __attribute__((aligned(16))) unsigned short Bu[BN * 64];
  __shared__ int toks[BM];

  int tid = threadIdx.x;
  // safe token for padded rows (block only runs when cnt >= 1)
  if (tid < BM) toks[tid] = (tid < rem) ? stok[base + m0 + tid] : stok[base];
  __syncthreads();

  int lane = tid & 63;
  int wid = tid >> 6;
  int srow = lane >> 3;                  // row within 8-row staging group == row&7
  int scol = ((lane & 7) ^ srow) << 3;   // swizzled source chunk, in shorts

  const unsigned short* wrow = gub + (size_t)e * (2 * (size_t)I_DIM) * H_DIM;
  const unsigned short* pa[4];
  const unsigned short* pg[4];
  const unsigned short* pu[4];
#pragma unroll
  for (int s = 0; s < 4; ++s) {
    int row = wid * 32 + s * 8 + srow;
    pa[s] = hb + (size_t)toks[row] * H_DIM + scol;
    pg[s] = wrow + (size_t)(n0 + row) * H_DIM + scol;
    pu[s] = wrow + (size_t)(I_DIM + n0 + row) * H_DIM + scol;
  }

  int lm = lane & 15;
  int q = lane >> 4;
  int wm = (wid >> 1) * 64;
  int wn = (wid & 1) * 64;
  // swizzled read cols (shorts): chunk (ks*4+q) ^ (lm&7)
  int rc0 = ((q ^ (lm & 7)) << 3);
  int rc1 = (((4 + q) ^ (lm & 7)) << 3);

  f32x4 accg[4][4] = {};
  f32x4 accu[4][4] = {};

  // prologue: stage A tile 0 (4 loads/thread) into As[0]
#pragma unroll
  for (int s = 0; s < 4; ++s)
    gload16(&As[0][(wid * 32 + s * 8) * 64], pa[s]);

  int cur = 0;
  for (int kb = 0; kb < H_DIM; kb += BK) {
    // stage B(t): 8 loads/thread (needed this iter -> drained below)
#pragma unroll
    for (int s = 0; s < 4; ++s) {
      gload16(&Bg[(wid * 32 + s * 8) * 64], pg[s] + kb);
      gload16(&Bu[(wid * 32 + s * 8) * 64], pu[s] + kb);
    }
    if (kb + BK < H_DIM) {
      // stage A(t+1): 4 loads/thread -> allowed to stay in flight (vmcnt 4)
#pragma unroll
      for (int s = 0; s < 4; ++s)
        gload16(&As[cur ^ 1][(wid * 32 + s * 8) * 64], pa[s] + kb + BK);
      __builtin_amdgcn_sched_barrier(0);
      asm volatile("s_waitcnt vmcnt(4)" ::: "memory");
    } else {
      __builtin_amdgcn_sched_barrier(0);
      asm volatile("s_waitcnt vmcnt(0)" ::: "memory");
    }
    __builtin_amdgcn_s_barrier();
    __builtin_amdgcn_sched_barrier(0);
#pragma unroll
    for (int ks = 0; ks < 2; ++ks) {
      int ko = ks ? rc1 : rc0;
      bf16x8 a[4], bg[4], bu[4];
#pragma unroll
      for (int i = 0; i < 4; ++i)
        a[i] = *(const bf16x8*)&As[cur][(wm + i * 16 + lm) * 64 + ko];
#pragma unroll
      for (int j = 0; j < 4; ++j) {
        bg[j] = *(const bf16x8*)&Bg[(wn + j * 16 + lm) * 64 + ko];
        bu[j] = *(const bf16x8*)&Bu[(wn + j * 16 + lm) * 64 + ko];
      }
#pragma unroll
      for (int i = 0; i < 4; ++i)
#pragma unroll
        for (int j = 0; j < 4; ++j) {
          accg[i][j] = __builtin_amdgcn_mfma_f32_16x16x32_bf16(a[i], bg[j], accg[i][j], 0, 0, 0);
          accu[i][j] = __builtin_amdgcn_mfma_f32_16x16x32_bf16(a[i], bu[j], accu[i][j], 0, 0, 0);
        }
    }
    __builtin_amdgcn_sched_barrier(0);
    __builtin_amdgcn_s_barrier();   // protects Bg/Bu + As[cur] overwrite next iter
    cur ^= 1;
  }

  // epilogue: act = silu(gate)*up, bf16 store. D layout: row=q*4+reg, col=lane&15.
#pragma unroll
  for (int i = 0; i < 4; ++i) {
    int mb = wm + i * 16 + q * 4;
#pragma unroll
    for (int r = 0; r < 4; ++r) {
      int m = mb + r;
      if (m < rem) {
        size_t rowoff = (size_t)(base + m0 + m) * I_DIM + n0;
#pragma unroll
        for (int j = 0; j < 4; ++j) {
          int n = wn + j * 16 + lm;
          float g = accg[i][j][r];
          float u = accu[i][j][r];
          float aa = (g / (1.0f + __expf(-g))) * u;
          act[rowoff + n] = f2bf(aa);
        }
      }
    }
  }
}

// ---------------------------------------------- down GEMM (bf16) * weight ---
// BK=64, (256,3), A-prefetch w/ counted vmcnt (r8 proven).
__global__ __launch_bounds__(256, 3) void gemm2_bf16_kernel(
    const unsigned short* __restrict__ act, const unsigned short* __restrict__ dwb,
    const int* __restrict__ offsets, const float* __restrict__ sw,
    float* __restrict__ dout) {
  int e = blockIdx.z;
  int base = offsets[e];
  int cnt = offsets[e + 1] - base;
  int m0 = blockIdx.y * BM;
  if (m0 >= cnt) return;
  int n0 = blockIdx.x * BN;
  int rem = cnt - m0;

  __shared__ __attribute__((aligned(16))) unsigned short As[2][BM * 64];
  __shared__ __attribute__((aligned(16))) unsigned short Bs[BN * 64];
  __shared__ float wsl[BM];

  int tid = threadIdx.x;
  if (tid < BM) wsl[tid] = (tid < rem) ? sw[base + m0 + tid] : 0.f;
  __syncthreads();

  int lane = tid & 63;
  int wid = tid >> 6;
  int srow = lane >> 3;
  int scol = ((lane & 7) ^ srow) << 3;

  const unsigned short* dp = dwb + (size_t)e * ((size_t)H_DIM * I_DIM);
  const unsigned short* pa[4];
  const unsigned short* pb[4];
#pragma unroll
  for (int s = 0; s < 4; ++s) {
    int row = wid * 32 + s * 8 + srow;
    pa[s] = act + (size_t)(base + m0 + row) * I_DIM + scol;
    pb[s] = dp + (size_t)(n0 + row) * I_DIM + scol;
  }

  int lm = lane & 15;
  int q = lane >> 4;
  int wm = (wid >> 1) * 64;
  int wn = (wid & 1) * 64;
  int rc0 = ((q ^ (lm & 7)) << 3);
  int rc1 = (((4 + q) ^ (lm & 7)) << 3);

  f32x4 acc[4][4] = {};

  // prologue: stage A (act) tile 0
#pragma unroll
  for (int s = 0; s < 4; ++s)
    gload16(&As[0][(wid * 32 + s * 8) * 64], pa[s]);

  int cur = 0;
  for (int kb = 0; kb < I_DIM; kb += BK) {
    // stage B(t): needed this iter
#pragma unroll
    for (int s = 0; s < 4; ++s)
      gload16(&Bs[(wid * 32 + s * 8) * 64], pb[s] + kb);
    if (kb + BK < I_DIM) {
      // stage A(t+1): stays in flight across the barrier
#pragma unroll
      for (int s = 0; s < 4; ++s)
        gload16(&As[cur ^ 1][(wid * 32 + s * 8) * 64], pa[s] + kb + BK);
      __builtin_amdgcn_sched_barrier(0);
      asm volatile("s_waitcnt vmcnt(4)" ::: "memory");
    } else {
      __builtin_amdgcn_sched_barrier(0);
      asm volatile("s_waitcnt vmcnt(0)" ::: "memory");
    }
    __builtin_amdgcn_s_barrier();
    __builtin_amdgcn_sched_barrier(0);
#pragma unroll
    for (int ks = 0; ks < 2; ++ks) {
      int ko = ks ? rc1 : rc0;
      bf16x8 a[4], b[4];
#pragma unroll
      for (int i = 0; i < 4; ++i)
        a[i] = *(const bf16x8*)&As[cur][(wm + i * 16 + lm) * 64 + ko];
#pragma unroll
      for (int j = 0; j < 4; ++j)
        b[j] = *(const bf16x8*)&Bs[(wn + j * 16 + lm) * 64 + ko];
#pragma unroll
      for (int i = 0; i < 4; ++i)
#pragma unroll
        for (int j = 0; j < 4; ++j)
          acc[i][j] = __builtin_amdgcn_mfma_f32_16x16x32_bf16(a[i], b[j], acc[i][j], 0, 0, 0);
    }
    __builtin_amdgcn_sched_barrier(0);
    __builtin_amdgcn_s_barrier();   // protects Bs + As[cur] overwrite next iter
    cur ^= 1;
  }

#pragma unroll
  for (int i = 0; i < 4; ++i) {
    int mb = wm + i * 16 + q * 4;
#pragma unroll
    for (int r = 0; r < 4; ++r) {
      int m = mb + r;
      if (m < rem) {
        float w = wsl[m];
        size_t rowoff = (size_t)(base + m0 + m) * H_DIM + n0;
#pragma unroll
        for (int j = 0; j < 4; ++j)
          dout[rowoff + wn + j * 16 + lm] = acc[i][j][r] * w;
      }
    }
  }
}

// ==================== OLD PATH (fallback if workspace too small) =============
__global__ __launch_bounds__(256, 2) void gemm1_kernel(
    const float* __restrict__ hidden, const float* __restrict__ gu,
    const int* __restrict__ offsets, const int* __restrict__ stok,
    unsigned short* __restrict__ act) {
  int e = blockIdx.z;
  int base = offsets[e];
  int cnt = offsets[e + 1] - base;
  int m0 = blockIdx.y * BM;
  if (m0 >= cnt) return;
  int n0 = blockIdx.x * BN;
  int rem = cnt - m0;

  __shared__ unsigned short As[BM * LDKO];
  __shared__ unsigned short Bg[BM * LDKO];
  __shared__ unsigned short Bu[BM * LDKO];
  __shared__ int toks[BM];

  int tid = threadIdx.x;
  if (tid < BM) toks[tid] = (tid < rem) ? stok[base + m0 + tid] : -1;
  __syncthreads();

  int lane = tid & 63;
  int wid = tid >> 6;
  int wm = (wid >> 1) * 64;
  int wn = (wid & 1) * 64;
  int lm = lane & 15;
  int q = lane >> 4;

  f32x4 accg[4][4] = {};
  f32x4 accu[4][4] = {};
  const float* gup = gu + (size_t)e * (2 * (size_t)I_DIM * H_DIM);

  for (int kb = 0; kb < H_DIM; kb += 64) {
#pragma unroll
    for (int s = 0; s < 8; ++s) {
      int task = tid + s * 256;
      int row = task >> 4;
      int cg = (task & 15) << 2;
      int tok = toks[row];
      float x0 = 0.f, x1 = 0.f, x2 = 0.f, x3 = 0.f;
      if (tok >= 0) {
        f32x4 v = *(const f32x4*)(hidden + (size_t)tok * H_DIM + kb + cg);
        x0 = v[0]; x1 = v[1]; x2 = v[2]; x3 = v[3];
      }
      *(unsigned long long*)&As[row * LDKO + cg] = pack4bf(x0, x1, x2, x3);
    }
#pragma unroll
    for (int s = 0; s < 8; ++s) {
      int task = tid + s * 256;
      int row = task >> 4;
      int cg = (task & 15) << 2;
      f32x4 vg = *(const f32x4*)(gup + (size_t)(n0 + row) * H_DIM + kb + cg);
      f32x4 vu = *(const f32x4*)(gup + (size_t)(I_DIM + n0 + row) * H_DIM + kb + cg);
      *(unsigned long long*)&Bg[row * LDKO + cg] = pack4bf(vg[0], vg[1], vg[2], vg[3]);
      *(unsigned long long*)&Bu[row * LDKO + cg] = pack4bf(vu[0], vu[1], vu[2], vu[3]);
    }
    __syncthreads();
#pragma unroll
    for (int ks = 0; ks < 2; ++ks) {
      int ko = ks * 32 + q * 8;
      bf16x8 a[4], bg[4], bu[4];
#pragma unroll
      for (int i = 0; i < 4; ++i)
        a[i] = *(const bf16x8*)&As[(wm + i * 16 + lm) * LDKO + ko];
#pragma unroll
      for (int j = 0; j < 4; ++j) {
        bg[j] = *(const bf16x8*)&Bg[(wn + j * 16 + lm) * LDKO + ko];
        bu[j] = *(const bf16x8*)&Bu[(wn + j * 16 + lm) * LDKO + ko];
      }
#pragma unroll
      for (int i = 0; i < 4; ++i)
#pragma unroll
        for (int j = 0; j < 4; ++j) {
          accg[i][j] = __builtin_amdgcn_mfma_f32_16x16x32_bf16(a[i], bg[j], accg[i][j], 0, 0, 0);
          accu[i][j] = __builtin_amdgcn_mfma_f32_16x16x32_bf16(a[i], bu[j], accu[i][j], 0, 0, 0);
        }
    }
    __syncthreads();
  }

#pragma unroll
  for (int i = 0; i < 4; ++i) {
    int mb = wm + i * 16 + q * 4;
#pragma unroll
    for (int r = 0; r < 4; ++r) {
      int m = mb + r;
      if (m < rem) {
        size_t rowoff = (size_t)(base + m0 + m) * I_DIM + n0;
#pragma unroll
        for (int j = 0; j < 4; ++j) {
          int n = wn + j * 16 + lm;
          float g = accg[i][j][r];
          float u = accu[i][j][r];
          float aa = (g / (1.0f + __expf(-g))) * u;
          act[rowoff + n] = f2bf(aa);
        }
      }
    }
  }
}

__global__ __launch_bounds__(256, 2) void gemm2_kernel(
    const unsigned short* __restrict__ act, const float* __restrict__ dwn,
    const int* __restrict__ offsets, const float* __restrict__ sw,
    float* __restrict__ dout) {
  int e = blockIdx.z;
  int base = offsets[e];
  int cnt = offsets[e + 1] - base;
  int m0 = blockIdx.y * BM;
  if (m0 >= cnt) return;
  int n0 = blockIdx.x * BN;
  int rem = cnt - m0;

  __shared__ unsigned short As[BM * LDKO];
  __shared__ unsigned short Bs[BM * LDKO];
  __shared__ float wsl[BM];

  int tid = threadIdx.x;
  if (tid < BM) wsl[tid] = (tid < rem) ? sw[base + m0 + tid] : 0.f;

  int lane = tid & 63;
  int wid = tid >> 6;
  int wm = (wid >> 1) * 64;
  int wn = (wid & 1) * 64;
  int lm = lane & 15;
  int q = lane >> 4;

  f32x4 acc[4][4] = {};
  const float* dp = dwn + (size_t)e * ((size_t)H_DIM * I_DIM);
  const unsigned short* ap = act + (size_t)(base + m0) * I_DIM;

  for (int kb = 0; kb < I_DIM; kb += 64) {
#pragma unroll
    for (int s = 0; s < 4; ++s) {
      int task = tid + s * 256;
      int row = task >> 3;
      int cg = (task & 7) << 3;
      u32x4 v = *(const u32x4*)(ap + (size_t)row * I_DIM + kb + cg);
      *(u32x4*)&As[row * LDKO + cg] = v;
    }
#pragma unroll
    for (int s = 0; s < 8; ++s) {
      int task = tid + s * 256;
      int row = task >> 4;
      int cg = (task & 15) << 2;
      f32x4 v = *(const f32x4*)(dp + (size_t)(n0 + row) * I_DIM + kb + cg);
      *(unsigned long long*)&Bs[row * LDKO + cg] = pack4bf(v[0], v[1], v[2], v[3]);
    }
    __syncthreads();
#pragma unroll
    for (int ks = 0; ks < 2; ++ks) {
      int ko = ks * 32 + q * 8;
      bf16x8 a[4], b[4];
#pragma unroll
      for (int i = 0; i < 4; ++i)
        a[i] = *(const bf16x8*)&As[(wm + i * 16 + lm) * LDKO + ko];
#pragma unroll
      for (int j = 0; j < 4; ++j)
        b[j] = *(const bf16x8*)&Bs[(wn + j * 16 + lm) * LDKO + ko];
#pragma unroll
      for (int i = 0; i < 4; ++i)
#pragma unroll
        for (int j = 0; j < 4; ++j)
          acc[i][j] = __builtin_amdgcn_mfma_f32_16x16x32_bf16(a[i], b[j], acc[i][j], 0, 0, 0);
    }
    __syncthreads();
  }

#pragma unroll
  for (int i = 0; i < 4; ++i) {
    int mb = wm + i * 16 + q * 4;
#pragma unroll
    for (int r = 0; r < 4; ++r) {
      int m = mb + r;
      if (m < rem) {
        float w = wsl[m];
        size_t rowoff = (size_t)(base + m0 + m) * H_DIM + n0;
#pragma unroll
        for (int j = 0; j < 4; ++j)
          dout[rowoff + wn + j * 16 + lm] = acc[i][j][r] * w;
      }
    }
  }
}

// ------------------------------------------------------------------ combine ---
__global__ void combine_kernel(const f32x4* __restrict__ dout4,
                               const int* __restrict__ slot_of,
                               f32x4* __restrict__ out4) {
  int idx = blockIdx.x * 256 + threadIdx.x;   // over T*H/4 = 2M
  int t = idx >> 9;                           // H/4 = 512 float4 per token
  int c = idx & 511;
  int s0 = slot_of[t * 2];
  int s1 = slot_of[t * 2 + 1];
  f32x4 r = dout4[(size_t)s0 * 512 + c] + dout4[(size_t)s1 * 512 + c];
  out4[idx] = r;
}

// ----------------------------------------------------------------- launch ---
extern "C" void kernel_launch(void* const* d_in, const int* in_sizes, int n_in,
                              void* d_out, int out_size, void* d_ws, size_t ws_size,
                              hipStream_t stream) {
  const float* hidden = (const float*)d_in[0];
  const float* tw     = (const float*)d_in[1];
  const int*   ids    = (const int*)d_in[2];
  const float* gu     = (const float*)d_in[3];
  const float* dwn    = (const float*)d_in[4];
  float* out = (float*)d_out;
  char* ws = (char*)d_ws;

  // common routing scratch (first 128 KiB)
  int*   offsets = (int*)ws;
  int*   stok    = (int*)(ws + 256);
  float* swp     = (float*)(ws + 256 + 32768);
  int*   slot_of = (int*)(ws + 256 + 65536);
  const size_t base_off = 1 << 17;
  const size_t act_sz   = (size_t)(NSLOT + BM) * I_DIM * 2;    // bf16, +pad rows

  routing_kernel<<<1, 256, 0, stream>>>(tw, ids, offsets, stok, swp, slot_of);

  // new-path layout:
  //   [base_off]                hidden_bf16   16 MiB
  //   [w_off]                   W region     256 MiB:
  //       gemm1 phase: gu_bf16 (full 256 MiB)
  //       gemm2 phase: down_bf16 [0,128MiB) | dout fp32 [128,192MiB)
  //   [w_off + 256MiB]          act bf16     ~65 MiB
  const size_t hb_sz  = (size_t)T_TOK * H_DIM * 2;
  const size_t gu_sz  = (size_t)E_NUM * 2 * (size_t)I_DIM * H_DIM * 2;
  const size_t dwn_sz = (size_t)E_NUM * (size_t)H_DIM * I_DIM * 2;
  const size_t w_off  = base_off + hb_sz;
  const size_t need   = w_off + gu_sz + act_sz;

  if (ws_size >= need) {
    unsigned short* hb   = (unsigned short*)(ws + base_off);
    unsigned short* gub  = (unsigned short*)(ws + w_off);
    unsigned short* dwb  = (unsigned short*)(ws + w_off);            // aliases gub (dead after gemm1)
    float*          dout = (float*)(ws + w_off + dwn_sz);            // aliases gub tail
    unsigned short* act  = (unsigned short*)(ws + w_off + gu_sz);

    cvt_bf16_kernel<<<2048, 256, 0, stream>>>(hidden, hb, (long long)T_TOK * H_DIM / 8);
    cvt_bf16_kernel<<<2048, 256, 0, stream>>>(gu, gub, (long long)E_NUM * 2 * I_DIM * H_DIM / 8);
    gemm1_bf16_kernel<<<dim3(I_DIM / BN, NSLOT / BM, E_NUM), 256, 0, stream>>>(hb, gub, offsets, stok, act);
    cvt_bf16_kernel<<<2048, 256, 0, stream>>>(dwn, dwb, (long long)E_NUM * H_DIM * I_DIM / 8);
    gemm2_bf16_kernel<<<dim3(H_DIM / BN, NSLOT / BM, E_NUM), 256, 0, stream>>>(act, dwb, offsets, swp, dout);
    combine_kernel<<<(T_TOK * H_DIM / 4) / 256, 256, 0, stream>>>((const f32x4*)dout, slot_of, (f32x4*)out);
  } else {
    // fallback: previous fp32-staging path (fits in ~132 MiB)
    unsigned short* act  = (unsigned short*)(ws + base_off);
    float*          dout = (float*)(ws + base_off + act_sz);
    gemm1_kernel<<<dim3(I_DIM / BN, NSLOT / BM, E_NUM), 256, 0, stream>>>(hidden, gu, offsets, stok, act);
    gemm2_kernel<<<dim3(H_DIM / BN, NSLOT / BM, E_NUM), 256, 0, stream>>>(act, dwn, offsets, swp, dout);
    combine_kernel<<<(T_TOK * H_DIM / 4) / 256, 256, 0, stream>>>((const f32x4*)dout, slot_of, (f32x4*)out);
  }
}